// Round 12
// baseline (25.055 us; speedup 1.0000x reference)
//
#include <hip/hip_runtime.h>

#define NN 1024
#define DD 128

typedef float f32x4 __attribute__((ext_vector_type(4)));
typedef _Float16 f16x8 __attribute__((ext_vector_type(8)));

union H2 { unsigned u; _Float16 h[2]; };

__device__ __forceinline__ f16x8 cvt8(f32x4 a, f32x4 b) {
  f16x8 r;
  r[0] = (_Float16)a.x; r[1] = (_Float16)a.y; r[2] = (_Float16)a.z; r[3] = (_Float16)a.w;
  r[4] = (_Float16)b.x; r[5] = (_Float16)b.y; r[6] = (_Float16)b.z; r[7] = (_Float16)b.w;
  return r;
}

// LDS-only barrier (no vmcnt drain; K stores stay in flight).
__device__ __forceinline__ void bar_lds() {
  asm volatile("s_waitcnt lgkmcnt(0)" ::: "memory");
  __builtin_amdgcn_s_barrier();
  asm volatile("" ::: "memory");
}

// ONE kernel, ONE dispatch. Grid 64 blocks (i-tiles of 16), 512 thr = 8 waves.
// Wave w loops t=0..3 over j-windows j0 = t*256 + w*32, fully autonomously:
//   QK^T (swapped: lane=col=i=li, regs=rows j) -> exp -> K store,
//   online per-i-row (= per-thread-uniform) power-of-2 rescale,
//   dK += K'^T @ Y via R7's verified H2-pair ytp transpose (LDS, wave-private)
//   with B-frag = own K' registers. dK accumulates in c[8] f32x4 registers.
// No barriers / no LDS atomics in the loop. One bar_lds at the end, then an
// 8-wave LDS combine + coalesced dK store. No workspace, no second kernel.
__global__ __launch_bounds__(512, 2) void gk_all(const float* __restrict__ X,
                                                 const float* __restrict__ Y,
                                                 const int* __restrict__ hp,
                                                 float* __restrict__ out) {
  __shared__ __align__(16) char smem[8][8192];  // per-wave: ytp u32[128][16]; reused as f32[16][128] partial
  __shared__ float SredL[128];                  // [w][li] row-sum partials

  const int tid  = threadIdx.x;
  const int ib   = blockIdx.x;          // 0..63 (i block of 16)
  const int lane = tid & 63;
  const int w    = tid >> 6;            // wave 0..7
  const int g    = lane >> 4;           // k-group 0..3
  const int li   = lane & 15;

  const float fh = (float)hp[0];
  const float inv_h2 = 1.0f / (fh * fh);
  const float L2E = 1.44269504088896341f;

  unsigned* ytp = (unsigned*)smem[w];

  // ---- X fragments -> f16 frags + |x|^2 (prologue; xa regs die after) ----
  const float* Xr = X + (size_t)(ib * 16 + li) * DD;
  f16x8 xbf[4];
  float xx = 0.f;
  #pragma unroll
  for (int kt = 0; kt < 4; ++kt) {
    int d0 = kt * 32 + g * 8;
    f32x4 a = *(const f32x4*)(Xr + d0);
    f32x4 b = *(const f32x4*)(Xr + d0 + 4);
    #pragma unroll
    for (int c = 0; c < 4; ++c) xx += a[c] * a[c] + b[c] * b[c];
    xbf[kt] = cvt8(a, b);
  }
  xx += __shfl_xor(xx, 16); xx += __shfl_xor(xx, 32);

  // ---- running state ----
  float M = 0.f;          // running max of raw K for row i=li (this wave's j's)
  unsigned se = 254u;     // scale = 2^(se-127); K' = K*scale targeted to [2^12,2^13)
  float sp = 0.f;         // running raw row-sum for row i=li (this thread's slices)
  f32x4 c[8] = {};        // dK partial: c[dt][r] = P'(i=li, d=dt*16+4g+r), scaled by 2^(se-127)

  // ---- preload Y rows for t=0 (single buffer, reloaded in-place each iter) ----
  f32x4 ya[16];
  {
    const float* Yr0 = Y + (size_t)(w * 32 + li) * DD;
    const float* Yr1 = Yr0 + 16 * DD;
    #pragma unroll
    for (int kt = 0; kt < 4; ++kt) {
      int d0 = kt * 32 + g * 8;
      ya[kt * 4 + 0] = *(const f32x4*)(Yr0 + d0);
      ya[kt * 4 + 1] = *(const f32x4*)(Yr0 + d0 + 4);
      ya[kt * 4 + 2] = *(const f32x4*)(Yr1 + d0);
      ya[kt * 4 + 3] = *(const f32x4*)(Yr1 + d0 + 4);
    }
  }

  #pragma unroll
  for (int t = 0; t < 4; ++t) {
    const int j0 = t * 256 + w * 32;

    // ---- consume ya: norms + f16 frags (frees ya for next-iter reload) ----
    float yy0 = 0.f, yy1 = 0.f;
    #pragma unroll
    for (int kt = 0; kt < 4; ++kt)
      #pragma unroll
      for (int cc = 0; cc < 4; ++cc) {
        yy0 += ya[kt * 4 + 0][cc] * ya[kt * 4 + 0][cc] + ya[kt * 4 + 1][cc] * ya[kt * 4 + 1][cc];
        yy1 += ya[kt * 4 + 2][cc] * ya[kt * 4 + 2][cc] + ya[kt * 4 + 3][cc] * ya[kt * 4 + 3][cc];
      }
    f16x8 af0[4], af1[4];
    #pragma unroll
    for (int kt = 0; kt < 4; ++kt) {
      af0[kt] = cvt8(ya[kt * 4 + 0], ya[kt * 4 + 1]);   // row li
      af1[kt] = cvt8(ya[kt * 4 + 2], ya[kt * 4 + 3]);   // row li+16
    }

    // ---- issue next-iter Y loads into the SAME ya regs (hide under compute) ----
    if (t < 3) {
      const float* Yr0 = Y + (size_t)((t + 1) * 256 + w * 32 + li) * DD;
      const float* Yr1 = Yr0 + 16 * DD;
      #pragma unroll
      for (int kt = 0; kt < 4; ++kt) {
        int d0 = kt * 32 + g * 8;
        ya[kt * 4 + 0] = *(const f32x4*)(Yr0 + d0);
        ya[kt * 4 + 1] = *(const f32x4*)(Yr0 + d0 + 4);
        ya[kt * 4 + 2] = *(const f32x4*)(Yr1 + d0);
        ya[kt * 4 + 3] = *(const f32x4*)(Yr1 + d0 + 4);
      }
    }

    // ---- ytp transpose writes (H2 pairs, wave-private) + QK^T MFMAs ----
    f32x4 acc0 = {0.f, 0.f, 0.f, 0.f}, acc1 = {0.f, 0.f, 0.f, 0.f};
    #pragma unroll
    for (int kt = 0; kt < 4; ++kt) {
      int d0 = kt * 32 + g * 8;
      #pragma unroll
      for (int cc = 0; cc < 8; ++cc) {
        H2 pk; pk.h[0] = af0[kt][cc]; pk.h[1] = af1[kt][cc];
        ytp[(d0 + cc) * 16 + li] = pk.u;
      }
      acc0 = __builtin_amdgcn_mfma_f32_16x16x32_f16(af0[kt], xbf[kt], acc0, 0, 0, 0);
      acc1 = __builtin_amdgcn_mfma_f32_16x16x32_f16(af1[kt], xbf[kt], acc1, 0, 0, 0);
    }
    yy0 += __shfl_xor(yy0, 16); yy0 += __shfl_xor(yy0, 32);
    yy1 += __shfl_xor(yy1, 16); yy1 += __shfl_xor(yy1, 32);

    // ---- exp: raw K (f32), tile max, row-sum ----
    float Kr[8];
    float mt = 0.f;
    #pragma unroll
    for (int r = 0; r < 4; ++r) {
      float yj0 = __shfl(yy0, 4 * g + r);   // norm of row j0+4g+r
      float yj1 = __shfl(yy1, 4 * g + r);   // norm of row j0+16+4g+r
      float e0 = fminf((acc0[r] - 0.5f * (xx + yj0)) * inv_h2, 0.0f);
      float e1 = fminf((acc1[r] - 0.5f * (xx + yj1)) * inv_h2, 0.0f);
      Kr[r]     = exp2f(e0 * L2E);
      Kr[4 + r] = exp2f(e1 * L2E);
      mt = fmaxf(mt, fmaxf(Kr[r], Kr[4 + r]));
      sp += Kr[r] + Kr[4 + r];
    }
    // K store (16 li-rows x 4 g-quads per instr -> full 64B segments)
    {
      float* kb = out + (size_t)(ib * 16 + li) * NN + j0 + 4 * g;
      f32x4 k0 = { Kr[0], Kr[1], Kr[2], Kr[3] };
      f32x4 k1 = { Kr[4], Kr[5], Kr[6], Kr[7] };
      *(f32x4*)kb = k0;
      *(f32x4*)(kb + 16) = k1;
    }

    // ---- online rescale (per-thread-uniform: all this thread's work is row li) ----
    mt = fmaxf(mt, __shfl_xor(mt, 16)); mt = fmaxf(mt, __shfl_xor(mt, 32));
    float Mn = fmaxf(M, mt);
    unsigned e8 = (__float_as_uint(Mn) >> 23) & 0xffu;
    unsigned sen = 266u - e8; if (sen > 254u) sen = 254u;
    float fac = __uint_as_float((127u + sen - se) << 23);  // 2^(sen-se), ==1 when unchanged
    #pragma unroll
    for (int dt = 0; dt < 8; ++dt) {
      c[dt].x *= fac; c[dt].y *= fac; c[dt].z *= fac; c[dt].w *= fac;
    }
    M = Mn; se = sen;
    float scale = __uint_as_float(se << 23);               // 2^(se-127)

    // ---- B-frag = own scaled K' regs in H2-pair order (j, j+16) ----
    f16x8 bq;
    #pragma unroll
    for (int r = 0; r < 4; ++r) {
      bq[2 * r]     = (_Float16)(Kr[r] * scale);
      bq[2 * r + 1] = (_Float16)(Kr[4 + r] * scale);
    }

    asm volatile("" ::: "memory");   // ytp writes ordered before reads (same wave)

    // ---- dK accumulate: c[dt] += mfma(ytp-frag, bq) over this 32-j window ----
    #pragma unroll
    for (int dt = 0; dt < 8; ++dt) {
      f16x8 af = *(const f16x8*)((const char*)ytp + (dt * 16 + li) * 64 + g * 16);
      c[dt] = __builtin_amdgcn_mfma_f32_16x16x32_f16(af, bq, c[dt], 0, 0, 0);
    }
    asm volatile("" ::: "memory");   // reads done before next-iter ytp overwrite
  }

  // ---- epilogue: row sums, unscale, 8-wave LDS combine, coalesced dK store ----
  sp += __shfl_xor(sp, 16); sp += __shfl_xor(sp, 32);
  if (lane < 16) SredL[w * 16 + li] = sp;

  float invs = __uint_as_float((254u - se) << 23);   // 2^(127-se); 0 only when row ~0 (harmless)
  float* pw = (float*)smem[w];                       // reuse ytp region: [i=li][d] f32
  #pragma unroll
  for (int dt = 0; dt < 8; ++dt) {
    f32x4 v = { c[dt].x * invs, c[dt].y * invs, c[dt].z * invs, c[dt].w * invs };
    *(f32x4*)(pw + li * 128 + dt * 16 + 4 * g) = v;
  }
  bar_lds();   // the ONE barrier: all wave partials + SredL visible

  {
    int i = tid >> 5, dq = tid & 31;                 // 512 thr = 16 i x 32 d-quads
    f32x4 s = {0.f, 0.f, 0.f, 0.f};
    float st = 0.f;
    #pragma unroll
    for (int w2 = 0; w2 < 8; ++w2) {
      f32x4 p = *(const f32x4*)((const float*)smem[w2] + i * 128 + dq * 4);
      s.x += p.x; s.y += p.y; s.z += p.z; s.w += p.w;
      st += SredL[w2 * 16 + i];
    }
    f32x4 xv = *(const f32x4*)(X + (size_t)(ib * 16 + i) * DD + dq * 4);
    f32x4 r;
    r.x = (s.x - st * xv.x) * inv_h2;
    r.y = (s.y - st * xv.y) * inv_h2;
    r.z = (s.z - st * xv.z) * inv_h2;
    r.w = (s.w - st * xv.w) * inv_h2;
    *(f32x4*)(out + (size_t)NN * NN + (size_t)(ib * 16 + i) * DD + dq * 4) = r;
  }
}

extern "C" void kernel_launch(void* const* d_in, const int* in_sizes, int n_in,
                              void* d_out, int out_size, void* d_ws, size_t ws_size,
                              hipStream_t stream) {
  const float* X  = (const float*)d_in[0];
  const float* Y  = (const float*)d_in[1];
  const int*   hp = (const int*)d_in[2];
  float* out = (float*)d_out;

  hipLaunchKernelGGL(gk_all, dim3(64), dim3(512), 0, stream, X, Y, hp, out);
}